// Round 5
// baseline (155.079 us; speedup 1.0000x reference)
//
#include <hip/hip_runtime.h>

// (B, D, T, V) = (16, 128, 4096, 1024)
#define B_ 16
#define D_ 128
#define T_ 4096
#define V_ 1024

typedef _Float16 half8 __attribute__((ext_vector_type(8)));
typedef float float4v __attribute__((ext_vector_type(4)));

// ws layout:
//   [0,       4096)   : chsq (V floats) = 0.5*|c|^2
//   [4096,  266240)   : Bh   (4 kt x 1024 v x 32 kk) f16 hi split; byte addr =
//                        kt*65536 + v*64 + kk*2
//   [266240,528384)   : Bl   (same, lo split scaled by 2048)
//
// LESSONS:
//  R3/R4(old): forcing min-waves in __launch_bounds__ spills (FETCH blowup).
//  R5(old): hipLaunchCooperativeKernel fails under this harness.
//  R9: XOR-swizzle killed bank conflicts (4.3M->131K) -> ZERO time change.
//  R10: occupancy 19->37% (8 waves split v) -> ZERO time change.
//  R11: 2-chunk intervals + deferred folds -> REGRESSION 68.6->89.9us
//    (compiler scheduled doubled-acc chains conservatively; MfmaUtil 30->22).
//  => All shared-LDS protocol variants pinned at ~68us; no pipe accounts for
//     the 5150 cyc/chunk wall. Remaining suspect: the staging protocol itself
//     (block-wide fences serialize phases across all waves).
//  R12 (this): ablate the protocol. B private per-wave global->VGPR loads
//    (B = 512KB, L2-resident; chunk 16KB ~L1-resident), software pipeline
//    2 kt-steps ahead, 4 static reg buffers. NO barriers in the main loop.
//    A in regs as before. Fold = R3's proven form (absmax 0).

// Fused: split codebook into f16 hi/lo fragments AND compute chsq.
__global__ __launch_bounds__(256) void split_csq_kernel(const float* __restrict__ cb,
                                                        _Float16* __restrict__ Bh,
                                                        _Float16* __restrict__ Bl,
                                                        float* __restrict__ chsq) {
    const int g = blockIdx.x * 256 + threadIdx.x;  // 16384 threads
    const int v = g >> 4;
    const int k0 = (g & 15) << 3;
    const float* src = cb + (size_t)v * D_ + k0;
    half8 h, l;
    float s = 0.f;
#pragma unroll
    for (int j = 0; j < 8; ++j) {
        float c = src[j];
        _Float16 ch = (_Float16)c;
        h[j] = ch;
        l[j] = (_Float16)((c - (float)ch) * 2048.0f);
        s = fmaf(c, c, s);
    }
    const int kt = k0 >> 5;
    const int kk = k0 & 31;
    const size_t off = ((size_t)(kt * V_ + v)) * 32 + kk;
    *(half8*)(Bh + off) = h;
    *(half8*)(Bl + off) = l;
#pragma unroll
    for (int o = 1; o < 16; o <<= 1) s += __shfl_xor(s, o, 64);
    if ((g & 15) == 0) chsq[v] = 0.5f * s;
}

// Main kernel: block = 512 thr = 8 waves; tile = 128 t x all 1024 v.
// Wave wv: t-rows [(wv&3)*32,+32) (mt=2), v-half wn=wv>>2 (16 v per chunk).
// A fragments in registers. B fragments loaded PRIVATELY per wave from
// global (L1/L2-served), pipelined 2 kt-steps ahead in 4 register buffers.
// No block-wide sync in the main loop. Dual accumulators (absmax 0 proven):
//   acc1 = sum_k xh*ch ; acc2 = sum_k (xh*cl' + xl'*ch)   (lo pre-scaled 2048)
//   score = 0.5|c|^2 - (acc1 + acc2/2048); running argmin, ties -> lowest v.
__global__ __launch_bounds__(512) void vq_mfma(const float* __restrict__ latents,
                                               const float* __restrict__ codebook,
                                               const float* __restrict__ chsq,
                                               const _Float16* __restrict__ Bh,
                                               const _Float16* __restrict__ Bl,
                                               float* __restrict__ out_codes,
                                               float* __restrict__ out_q) {
    // A-stage (128x136 x2 halves = 69632 B); no B staging anymore.
    __shared__ __align__(16) char smem[69632];
    __shared__ float sChsq[V_];
    __shared__ int scode[128];
    __shared__ float sBestF[2][128];
    __shared__ int sBestV[2][128];

    const int tid = threadIdx.x;
    const int tl = tid & 63;
    const int wv = tid >> 6;       // 0..7
    const int wt = wv & 3;         // t-group
    const int wn = wv >> 2;        // v-half
    const int ln = tid & 15;       // MFMA col (n) / A row (m)
    const int q = (tid >> 4) & 3;  // quad
    const int b = blockIdx.x >> 5;           // 32 t-tiles of 128 per batch entry
    const int t00 = (blockIdx.x & 31) << 7;  // t-tile start

    _Float16* AhS = (_Float16*)smem;  // [128][136] (+8 pad)
    _Float16* AlS = AhS + 128 * 136;

    // ---- stage chsq into LDS ----
#pragma unroll
    for (int i = 0; i < V_ / 512; ++i) sChsq[tid + i * 512] = chsq[tid + i * 512];

    // ---- stage A tile (128 t x 128 d), f16 split, [t][k] rows ----
    {
        const int arow = tid & 127;
        const int adh = tid >> 7;  // 0..3, 32-d slab
        const float* xp = latents + (size_t)b * D_ * T_ + t00 + arow;
#pragma unroll
        for (int i = 0; i < 4; ++i) {
            const int d0 = adh * 32 + i * 8;
            float x[8];
#pragma unroll
            for (int j = 0; j < 8; ++j) x[j] = xp[(size_t)(d0 + j) * T_];
            half8 h, l;
#pragma unroll
            for (int j = 0; j < 8; ++j) {
                _Float16 xh = (_Float16)x[j];
                h[j] = xh;
                l[j] = (_Float16)((x[j] - (float)xh) * 2048.0f);
            }
            *(half8*)(AhS + arow * 136 + d0) = h;
            *(half8*)(AlS + arow * 136 + d0) = l;
        }
    }
    __syncthreads();

    // ---- extract A fragments to registers: wave owns rows wt*32..+32 ----
    half8 ah[4][2], al[4][2];  // [kt][mt] : 64 VGPRs
#pragma unroll
    for (int kt = 0; kt < 4; ++kt)
#pragma unroll
        for (int mt = 0; mt < 2; ++mt) {
            const int row = wt * 32 + mt * 16 + ln;
            ah[kt][mt] = *(const half8*)(AhS + row * 136 + kt * 32 + q * 8);
            al[kt][mt] = *(const half8*)(AlS + row * 136 + kt * 32 + q * 8);
        }

    const char* BhB = (const char*)Bh;
    const char* BlB = (const char*)Bl;
    // per-wave B address for pipeline step s (s = c*4 + kt, 128 steps):
    //   off(s) = (s&3)*65536 + (s>>2)*2048 + rowoff
    const int rowoff = (wn * 16 + ln) * 64 + q * 16;

    // ---- prologue: prefetch steps 0,1 into slots 0,1 ----
    half8 pbh[4], pbl[4];  // 4 rotating kt-step buffers (static indexing only)
    {
        const int o0 = rowoff;                  // s=0: kt=0,c=0
        const int o1 = 65536 + rowoff;          // s=1: kt=1,c=0
        pbh[0] = *(const half8*)(BhB + o0);
        pbl[0] = *(const half8*)(BlB + o0);
        pbh[1] = *(const half8*)(BhB + o1);
        pbl[1] = *(const half8*)(BlB + o1);
    }
    __syncthreads();  // A-stage region reads done block-wide (A regs final)

    float bestF[2][4];
    int bestv[2][4];
#pragma unroll
    for (int mt = 0; mt < 2; ++mt)
#pragma unroll
        for (int r = 0; r < 4; ++r) {
            bestF[mt][r] = 3.0e38f;
            bestv[mt][r] = 0;
        }

    for (int c = 0; c < 32; ++c) {
        float4v acc1[2], acc2[2];  // [mt]
#pragma unroll
        for (int mt = 0; mt < 2; ++mt) {
            acc1[mt] = (float4v){0.f, 0.f, 0.f, 0.f};
            acc2[mt] = (float4v){0.f, 0.f, 0.f, 0.f};
        }
#pragma unroll
        for (int kt = 0; kt < 4; ++kt) {
            // prefetch step s+2 into slot (kt+2)&3; wrap at the tail
            // (redundant re-load of steps 0,1 -- harmless L1 hits)
            {
                const int s2 = (c * 4 + kt + 2) & 127;
                const int o = ((s2 & 3) << 16) + ((s2 >> 2) << 11) + rowoff;
                pbh[(kt + 2) & 3] = *(const half8*)(BhB + o);
                pbl[(kt + 2) & 3] = *(const half8*)(BlB + o);
            }
            __builtin_amdgcn_s_setprio(1);
#pragma unroll
            for (int mt = 0; mt < 2; ++mt) {
                acc1[mt] = __builtin_amdgcn_mfma_f32_16x16x32_f16(
                    ah[kt][mt], pbh[kt], acc1[mt], 0, 0, 0);
                acc2[mt] = __builtin_amdgcn_mfma_f32_16x16x32_f16(
                    ah[kt][mt], pbl[kt], acc2[mt], 0, 0, 0);
                acc2[mt] = __builtin_amdgcn_mfma_f32_16x16x32_f16(
                    al[kt][mt], pbh[kt], acc2[mt], 0, 0, 0);
            }
            __builtin_amdgcn_s_setprio(0);
        }
        // fold scores into running argmin
        {
            const int n = c * 32 + wn * 16 + ln;
            const float csq = sChsq[n];
#pragma unroll
            for (int mt = 0; mt < 2; ++mt)
#pragma unroll
                for (int r = 0; r < 4; ++r) {
                    const float score =
                        csq - (acc1[mt][r] + acc2[mt][r] * (1.0f / 2048.0f));
                    if (score < bestF[mt][r]) {  // strict < => lowest v on ties
                        bestF[mt][r] = score;
                        bestv[mt][r] = n;
                    }
                }
        }
    }

    // cross-lane argmin over the 16-col group; ties -> lowest v
#pragma unroll
    for (int off = 1; off < 16; off <<= 1) {
#pragma unroll
        for (int mt = 0; mt < 2; ++mt)
#pragma unroll
            for (int r = 0; r < 4; ++r) {
                const float of = __shfl_xor(bestF[mt][r], off, 64);
                const int ov = __shfl_xor(bestv[mt][r], off, 64);
                if (of < bestF[mt][r] || (of == bestF[mt][r] && ov < bestv[mt][r])) {
                    bestF[mt][r] = of;
                    bestv[mt][r] = ov;
                }
            }
    }

    // per-wave per-half argmin: lanes ln==0 publish rows m = wt*32+mt*16+q*4+r
    if (ln == 0) {
#pragma unroll
        for (int mt = 0; mt < 2; ++mt)
#pragma unroll
            for (int r = 0; r < 4; ++r) {
                const int m = wt * 32 + mt * 16 + q * 4 + r;
                sBestF[wn][m] = bestF[mt][r];
                sBestV[wn][m] = bestv[mt][r];
            }
    }
    __syncthreads();

    // combine the two v-halves (lexicographic (f, v) => global lowest-v argmin)
    if (tid < 128) {
        const float f0 = sBestF[0][tid];
        const float f1 = sBestF[1][tid];
        const int v0 = sBestV[0][tid];
        const int v1 = sBestV[1][tid];
        const int vb = (f1 < f0 || (f1 == f0 && v1 < v0)) ? v1 : v0;
        scode[tid] = vb;
        out_codes[(size_t)b * T_ + t00 + tid] = (float)vb;
    }
    __syncthreads();

    // gather-write quantized[b, d, t00+row] = codebook[code, d]; coalesced
    {
        const int row = tid & 127;
        const int dq = tid >> 7;
        const int code = scode[row];
        const float* crow = codebook + (size_t)code * D_;
        float* qp = out_q + (size_t)b * D_ * T_ + t00 + row;
#pragma unroll
        for (int i = 0; i < 32; ++i) {
            const int d = dq * 32 + i;
            qp[(size_t)d * T_] = crow[d];
        }
    }
}

extern "C" void kernel_launch(void* const* d_in, const int* in_sizes, int n_in,
                              void* d_out, int out_size, void* d_ws, size_t ws_size,
                              hipStream_t stream) {
    const float* latents = (const float*)d_in[0];   // (B, D, T) f32
    const float* codebook = (const float*)d_in[1];  // (V, D) f32

    float* out_codes = (float*)d_out;        // (B, T) codes as f32 values
    float* out_q = (float*)d_out + B_ * T_;  // (B, D, T) quantized f32

    float* chsq = (float*)d_ws;
    _Float16* Bh = (_Float16*)((char*)d_ws + 4096);
    _Float16* Bl = (_Float16*)((char*)d_ws + 4096 + 262144);

    split_csq_kernel<<<(V_ * 16) / 256, 256, 0, stream>>>(codebook, Bh, Bl, chsq);
    vq_mfma<<<(B_ * T_) / 128, 512, 0, stream>>>(latents, codebook, chsq, Bh, Bl,
                                                 out_codes, out_q);
}